// Round 2
// baseline (211.474 us; speedup 1.0000x reference)
//
#include <hip/hip_runtime.h>

#define EPSF 1e-8f

__device__ __forceinline__ float frcp(float x) { return __builtin_amdgcn_rcpf(x); }
__device__ __forceinline__ float frsq(float x) { return __builtin_amdgcn_rsqf(x); }
__device__ __forceinline__ float sq(float x) { return x * x; }

// normalize_points on (x, y, 1): zero-feature fix, unit-norm feats, sgn(hom)=+1 always.
__device__ __forceinline__ float2 norm_pt(float x, float y) {
    if (x == 0.0f && y == 0.0f) { x = 1.0f; y = 1.0f; }
    float nrm = sqrtf(x * x + y * y);
    float inv = frcp(fmaxf(nrm, EPSF));
    return make_float2(x * inv, y * inv);
}

// cross-ratio of (p1, p2, i1(line), i2(line)) with p1,p2 unit-normalized.
// hom coords are all 1 -> they cancel in every distance.
__device__ __forceinline__ float edge_cr(float x1, float y1, float x2, float y2) {
    // line = cross((x1,y1,1),(x2,y2,1))
    float a = y1 - y2;
    float b = x2 - x1;
    float c = x1 * y2 - y1 * x2;
    float n2 = fmaxf(a * a + b * b, EPSF);
    float rn2 = frcp(n2);
    float x0 = -c * a * rn2;
    float y0 = -c * b * rn2;
    float t  = sqrtf(fmaxf(1.0f - c * c * rn2, 0.0f));
    float inv = frsq(n2);
    float px = -b * inv, py = a * inv;
    float2 q1 = norm_pt(x0 + t * px, y0 + t * py);
    float2 q2 = norm_pt(x0 - t * px, y0 - t * py);
    float d12 = sqrtf(sq(x1 - x2)   + sq(y1 - y2));
    float d34 = sqrtf(sq(q1.x - q2.x) + sq(q1.y - q2.y));
    float d13 = sqrtf(sq(x1 - q1.x) + sq(y1 - q1.y));
    float d24 = sqrtf(sq(x2 - q2.x) + sq(y2 - q2.y));
    float cr = d12 * d34 * frcp(d13 * d24 + EPSF);
    return fminf(fmaxf(cr, -5.0f), 5.0f);
}

// numerically stable softplus matching jax.nn.softplus
__device__ __forceinline__ float softplus(float x) {
    return fmaxf(x, 0.0f) + log1pf(expf(-fabsf(x)));
}

// block reduce of two floats, then one double atomicAdd each
__device__ __forceinline__ void block_reduce2(float v0, float v1, double* a0, double* a1) {
    #pragma unroll
    for (int o = 32; o > 0; o >>= 1) {
        v0 += __shfl_down(v0, o, 64);
        v1 += __shfl_down(v1, o, 64);
    }
    __shared__ float s0[8], s1[8];
    int lane = threadIdx.x & 63, wid = threadIdx.x >> 6;
    if (lane == 0) { s0[wid] = v0; s1[wid] = v1; }
    __syncthreads();
    if (threadIdx.x == 0) {
        float t0 = 0.0f, t1 = 0.0f;
        int nw = blockDim.x >> 6;
        for (int w = 0; w < nw; ++w) { t0 += s0[w]; t1 += s1[w]; }
        atomicAdd(a0, (double)t0);
        if (a1) atomicAdd(a1, (double)t1);
    }
}

__global__ void pos_kernel(const float* __restrict__ z, const int* __restrict__ ei,
                           const int* __restrict__ bsp, int E, int N,
                           double* __restrict__ acc) {
    int bs = bsp[0];
    const int* src = ei;
    const int* dst = ei + E;
    float lsum = 0.0f, lcnt = 0.0f;
    int stride = gridDim.x * blockDim.x;
    for (int i = blockIdx.x * blockDim.x + threadIdx.x; i < E; i += stride) {
        int s = src[i], d = dst[i];
        float m = (s < bs && d < bs) ? 1.0f : 0.0f;
        unsigned si = min((unsigned)s, (unsigned)(N - 1));
        unsigned di = min((unsigned)d, (unsigned)(N - 1));
        float2 zs = *(const float2*)(z + 2u * si);
        float2 zd = *(const float2*)(z + 2u * di);
        float2 p1 = norm_pt(zs.x, zs.y);
        float2 p2 = norm_pt(zd.x, zd.y);
        float cr = edge_cr(p1.x, p1.y, p2.x, p2.y);
        lsum += softplus(-cr) * m;
        lcnt += m;
    }
    block_reduce2(lsum, lcnt, &acc[0], &acc[1]);
}

__global__ void neg_kernel(const float* __restrict__ z, const int* __restrict__ ei,
                           int E, int N, double* __restrict__ acc) {
    const int* src = ei;
    const int* dst = ei + E;
    float lsum = 0.0f;
    int stride = gridDim.x * blockDim.x;
    for (int i = blockIdx.x * blockDim.x + threadIdx.x; i < E; i += stride) {
        unsigned si = min((unsigned)src[i], (unsigned)(N - 1));
        unsigned di = min((unsigned)dst[i], (unsigned)(N - 1));
        float2 zs = *(const float2*)(z + 2u * si);
        float2 zd = *(const float2*)(z + 2u * di);
        float2 p1 = norm_pt(zs.x, zs.y);
        float2 p2 = norm_pt(zd.x, zd.y);
        float cr = edge_cr(p1.x, p1.y, p2.x, p2.y);
        lsum += softplus(cr);
    }
    block_reduce2(lsum, 0.0f, &acc[2], nullptr);
}

__global__ void reg_kernel(const float* __restrict__ z, const int* __restrict__ ridx,
                           int nreg, int N, double* __restrict__ acc) {
    int t = threadIdx.x;
    int npairs = nreg * (nreg - 1) / 2;
    float v = 0.0f;
    if (t < npairs) {
        // map t -> (i, j) of triu_indices(nreg, k=1), row-major
        int idx = t, i = 0, cnt = nreg - 1;
        while (idx >= cnt) { idx -= cnt; ++i; --cnt; }
        int j = i + 1 + idx;
        unsigned si = min((unsigned)ridx[i], (unsigned)(N - 1));
        unsigned di = min((unsigned)ridx[j], (unsigned)(N - 1));
        float2 zs = *(const float2*)(z + 2u * si);
        float2 zd = *(const float2*)(z + 2u * di);
        float2 p1 = norm_pt(zs.x, zs.y);
        float2 p2 = norm_pt(zd.x, zd.y);
        float cr = edge_cr(p1.x, p1.y, p2.x, p2.y);
        // cross_ratio(p1,p2,i1,i2) == cross_ratio(i1,i2,p1,p2): identical num & den
        v = fabsf(cr * cr - 1.0f);
    }
    #pragma unroll
    for (int o = 32; o > 0; o >>= 1) v += __shfl_down(v, o, 64);
    if (t == 0) acc[3] = (double)v;
}

__global__ void fin_kernel(const double* __restrict__ acc, float* __restrict__ out,
                           int nneg, int npairs) {
    double pos = acc[0] / fmax(acc[1], 1.0);
    double neg = acc[2] / (double)nneg;
    double reg = acc[3] / (double)npairs;
    double tot = pos + neg + 0.1 * reg;
    tot = fmin(fmax(tot, 0.0), 5.0);
    out[0] = (float)tot;
}

extern "C" void kernel_launch(void* const* d_in, const int* in_sizes, int n_in,
                              void* d_out, int out_size, void* d_ws, size_t ws_size,
                              hipStream_t stream) {
    const float* z   = (const float*)d_in[0];
    const int* ei    = (const int*)d_in[1];
    const int* nei   = (const int*)d_in[2];
    const int* ridx  = (const int*)d_in[3];
    const int* bsp   = (const int*)d_in[4];
    float* out = (float*)d_out;

    int N    = in_sizes[0] / 2;
    int E    = in_sizes[1] / 2;
    int Nn   = in_sizes[2] / 2;
    int nreg = in_sizes[3];

    double* acc = (double*)d_ws;
    hipMemsetAsync(acc, 0, 4 * sizeof(double), stream);

    const int threads = 256;
    int gp = (E + threads - 1) / threads;  if (gp > 2048) gp = 2048;
    int gn = (Nn + threads - 1) / threads; if (gn > 2048) gn = 2048;

    pos_kernel<<<gp, threads, 0, stream>>>(z, ei, bsp, E, N, acc);
    neg_kernel<<<gn, threads, 0, stream>>>(z, nei, Nn, N, acc);
    reg_kernel<<<1, 64, 0, stream>>>(z, ridx, nreg, N, acc);
    fin_kernel<<<1, 1, 0, stream>>>(acc, out, Nn, nreg * (nreg - 1) / 2);
}

// Round 4
// 125.279 us; speedup vs baseline: 1.6880x; 1.6880x over previous
//
#include <hip/hip_runtime.h>
#include <hip/hip_fp16.h>

#define EPSF 1e-8f

typedef int iv4 __attribute__((ext_vector_type(4)));

__device__ __forceinline__ float frcp(float x) { return __builtin_amdgcn_rcpf(x); }
__device__ __forceinline__ float frsq(float x) { return __builtin_amdgcn_rsqf(x); }
__device__ __forceinline__ float sq(float x) { return x * x; }

// ln(1 + e^{-x}) for x >= 0, via HW v_exp_f32 (2^x) / v_log_f32 (log2 x)
__device__ __forceinline__ float sp_neg(float x) {
    return 0.69314718f * __builtin_amdgcn_logf(1.0f + __builtin_amdgcn_exp2f(-x * 1.44269504f));
}

// ---- full-math helpers (kept for the 45-pair reg term, exact fidelity) ----
__device__ __forceinline__ float2 norm_pt(float x, float y) {
    if (x == 0.0f && y == 0.0f) { x = 1.0f; y = 1.0f; }
    float nrm = sqrtf(x * x + y * y);
    float inv = frcp(fmaxf(nrm, EPSF));
    return make_float2(x * inv, y * inv);
}

__device__ __forceinline__ float edge_cr_full(float x1, float y1, float x2, float y2) {
    float a = y1 - y2;
    float b = x2 - x1;
    float c = x1 * y2 - y1 * x2;
    float n2 = fmaxf(a * a + b * b, EPSF);
    float rn2 = frcp(n2);
    float x0 = -c * a * rn2;
    float y0 = -c * b * rn2;
    float t  = sqrtf(fmaxf(1.0f - c * c * rn2, 0.0f));
    float inv = frsq(n2);
    float px = -b * inv, py = a * inv;
    float2 q1 = norm_pt(x0 + t * px, y0 + t * py);
    float2 q2 = norm_pt(x0 - t * px, y0 - t * py);
    float d12 = sqrtf(sq(x1 - x2)   + sq(y1 - y2));
    float d34 = sqrtf(sq(q1.x - q2.x) + sq(q1.y - q2.y));
    float d13 = sqrtf(sq(x1 - q1.x) + sq(y1 - q1.y));
    float d24 = sqrtf(sq(x2 - q2.x) + sq(y2 - q2.y));
    float cr = d12 * d34 * frcp(d13 * d24 + EPSF);
    return fminf(fmaxf(cr, -5.0f), 5.0f);
}

// block reduce of two floats, then one double atomicAdd each
__device__ __forceinline__ void block_reduce2(float v0, float v1, double* a0, double* a1) {
    #pragma unroll
    for (int o = 32; o > 0; o >>= 1) {
        v0 += __shfl_down(v0, o, 64);
        v1 += __shfl_down(v1, o, 64);
    }
    __shared__ float s0[8], s1[8];
    int lane = threadIdx.x & 63, wid = threadIdx.x >> 6;
    if (lane == 0) { s0[wid] = v0; s1[wid] = v1; }
    __syncthreads();
    if (threadIdx.x == 0) {
        float t0 = 0.0f, t1 = 0.0f;
        int nw = blockDim.x >> 6;
        for (int w = 0; w < nw; ++w) { t0 += s0[w]; t1 += s1[w]; }
        atomicAdd(a0, (double)t0);
        if (a1) atomicAdd(a1, (double)t1);
    }
}

// normalize z into a compact half2 table (4 MB for N=1M -> fits one XCD L2)
__global__ void norm_kernel(const float* __restrict__ z, __half2* __restrict__ tab, int N) {
    int stride = gridDim.x * blockDim.x;
    for (int i = blockIdx.x * blockDim.x + threadIdx.x; i < N; i += stride) {
        float2 p = ((const float2*)z)[i];
        float x = p.x, y = p.y;
        if (x == 0.0f && y == 0.0f) { x = 1.0f; y = 1.0f; }
        float inv = frcp(fmaxf(sqrtf(x * x + y * y), EPSF));
        tab[i] = __floats2half2_rn(x * inv, y * inv);
    }
}

// Fused pos+neg edge kernel. Blocks [0,gp) -> positive edges, [gp,grid) -> negative.
// Exact identity: ideal points i1,i2 coincide with p1,p2 (unit circle == null cone,
// line meets circle at the two points) => d13=d24=0, d34=d12 =>
// cr = d12*d34/(d13*d24 + 1e-8) == min(d12^2 * 1e8, 5) (ref f32 denominator is
// eps-dominated: d13*d24 ~ 1e-14).
template <bool USE_TAB>
__global__ void edge_kernel(const __half2* __restrict__ tab, const float* __restrict__ z,
                            const int* __restrict__ ei, int E,
                            const int* __restrict__ nei, int En,
                            const int* __restrict__ bsp, int N, int gp,
                            double* __restrict__ acc) {
    const bool is_pos = (int)blockIdx.x < gp;
    const int* idx;
    int cnt, nblk, blk0;
    if (is_pos) { idx = ei;  cnt = E;  nblk = gp;              blk0 = blockIdx.x; }
    else        { idx = nei; cnt = En; nblk = gridDim.x - gp;  blk0 = blockIdx.x - gp; }
    const int* src = idx;
    const int* dst = idx + cnt;
    const int bs = bsp[0];
    const unsigned nm1 = (unsigned)(N - 1);

    int nq = cnt >> 2;
    int tper = nblk * blockDim.x;
    float lsum = 0.0f, lcnt = 0.0f;

    for (int q = blk0 * blockDim.x + threadIdx.x; q < nq; q += tper) {
        iv4 s4 = __builtin_nontemporal_load((const iv4*)src + q);
        iv4 d4 = __builtin_nontemporal_load((const iv4*)dst + q);
        #pragma unroll
        for (int k = 0; k < 4; ++k) {
            int s = s4[k], d = d4[k];
            unsigned si = min((unsigned)s, nm1);
            unsigned di = min((unsigned)d, nm1);
            float x1, y1, x2, y2;
            if (USE_TAB) {
                float2 a = __half22float2(tab[si]);
                float2 b = __half22float2(tab[di]);
                x1 = a.x; y1 = a.y; x2 = b.x; y2 = b.y;
            } else {
                float2 a = ((const float2*)z)[si];
                float2 b = ((const float2*)z)[di];
                float2 pa = norm_pt(a.x, a.y);
                float2 pb = norm_pt(b.x, b.y);
                x1 = pa.x; y1 = pa.y; x2 = pb.x; y2 = pb.y;
            }
            float dx = x1 - x2, dy = y1 - y2;
            float u = dx * dx + dy * dy;
            float cr = fminf(u * 1e8f, 5.0f);
            float t = sp_neg(cr);            // softplus(-cr), cr >= 0
            if (is_pos) {
                float m = (s < bs && d < bs) ? 1.0f : 0.0f;
                lsum += t * m;
                lcnt += m;
            } else {
                lsum += cr + t;              // softplus(cr) = cr + softplus(-cr)
            }
        }
    }

    // tail edges [4*nq, cnt)
    if (blk0 == 0 && (int)threadIdx.x < (cnt & 3)) {
        int i = (nq << 2) + threadIdx.x;
        int s = src[i], d = dst[i];
        unsigned si = min((unsigned)s, nm1);
        unsigned di = min((unsigned)d, nm1);
        float x1, y1, x2, y2;
        if (USE_TAB) {
            float2 a = __half22float2(tab[si]);
            float2 b = __half22float2(tab[di]);
            x1 = a.x; y1 = a.y; x2 = b.x; y2 = b.y;
        } else {
            float2 a = ((const float2*)z)[si];
            float2 b = ((const float2*)z)[di];
            float2 pa = norm_pt(a.x, a.y);
            float2 pb = norm_pt(b.x, b.y);
            x1 = pa.x; y1 = pa.y; x2 = pb.x; y2 = pb.y;
        }
        float dx = x1 - x2, dy = y1 - y2;
        float cr = fminf((dx * dx + dy * dy) * 1e8f, 5.0f);
        float t = sp_neg(cr);
        if (is_pos) {
            float m = (s < bs && d < bs) ? 1.0f : 0.0f;
            lsum += t * m; lcnt += m;
        } else {
            lsum += cr + t;
        }
    }

    if (is_pos) block_reduce2(lsum, lcnt, &acc[0], &acc[1]);
    else        block_reduce2(lsum, 0.0f, &acc[2], nullptr);
}

// 45-pair regularizer: full original math, negligible cost
__global__ void reg_kernel(const float* __restrict__ z, const int* __restrict__ ridx,
                           int nreg, int N, double* __restrict__ acc) {
    int t = threadIdx.x;
    int npairs = nreg * (nreg - 1) / 2;
    float v = 0.0f;
    if (t < npairs) {
        int idx = t, i = 0, cnt = nreg - 1;
        while (idx >= cnt) { idx -= cnt; ++i; --cnt; }
        int j = i + 1 + idx;
        unsigned si = min((unsigned)ridx[i], (unsigned)(N - 1));
        unsigned di = min((unsigned)ridx[j], (unsigned)(N - 1));
        float2 zs = *(const float2*)(z + 2u * si);
        float2 zd = *(const float2*)(z + 2u * di);
        float2 p1 = norm_pt(zs.x, zs.y);
        float2 p2 = norm_pt(zd.x, zd.y);
        float cr = edge_cr_full(p1.x, p1.y, p2.x, p2.y);
        v = fabsf(cr * cr - 1.0f);   // cr1 == cr2 (identical num/den products)
    }
    #pragma unroll
    for (int o = 32; o > 0; o >>= 1) v += __shfl_down(v, o, 64);
    if (t == 0) acc[3] = (double)v;
}

__global__ void fin_kernel(const double* __restrict__ acc, float* __restrict__ out,
                           int nneg, int npairs) {
    double pos = acc[0] / fmax(acc[1], 1.0);
    double neg = acc[2] / (double)nneg;
    double reg = acc[3] / (double)npairs;
    double tot = pos + neg + 0.1 * reg;
    tot = fmin(fmax(tot, 0.0), 5.0);
    out[0] = (float)tot;
}

extern "C" void kernel_launch(void* const* d_in, const int* in_sizes, int n_in,
                              void* d_out, int out_size, void* d_ws, size_t ws_size,
                              hipStream_t stream) {
    const float* z  = (const float*)d_in[0];
    const int* ei   = (const int*)d_in[1];
    const int* nei  = (const int*)d_in[2];
    const int* ridx = (const int*)d_in[3];
    const int* bsp  = (const int*)d_in[4];
    float* out = (float*)d_out;

    int N    = in_sizes[0] / 2;
    int E    = in_sizes[1] / 2;
    int Nn   = in_sizes[2] / 2;
    int nreg = in_sizes[3];

    double* acc = (double*)d_ws;
    __half2* tab = (__half2*)((char*)d_ws + 256);
    size_t need = 256 + (size_t)N * sizeof(__half2);
    bool use_tab = (ws_size >= need);

    (void)hipMemsetAsync(acc, 0, 4 * sizeof(double), stream);

    const int threads = 256;
    const int gp = 1792, gn = 256;   // ~8:1 pos:neg work split, 2048 blocks total

    if (use_tab) {
        int gnorm = (N + threads * 4 - 1) / (threads * 4); if (gnorm > 1024) gnorm = 1024;
        norm_kernel<<<gnorm, threads, 0, stream>>>(z, tab, N);
        edge_kernel<true><<<gp + gn, threads, 0, stream>>>(tab, z, ei, E, nei, Nn, bsp, N, gp, acc);
    } else {
        edge_kernel<false><<<gp + gn, threads, 0, stream>>>(nullptr, z, ei, E, nei, Nn, bsp, N, gp, acc);
    }
    reg_kernel<<<1, 64, 0, stream>>>(z, ridx, nreg, N, acc);
    fin_kernel<<<1, 1, 0, stream>>>(acc, out, Nn, nreg * (nreg - 1) / 2);
}

// Round 5
// 123.378 us; speedup vs baseline: 1.7140x; 1.0154x over previous
//
#include <hip/hip_runtime.h>
#include <hip/hip_fp16.h>

#define EPSF 1e-8f
#define EPT 16  // edges per thread

typedef int iv4 __attribute__((ext_vector_type(4)));

__device__ __forceinline__ float frcp(float x) { return __builtin_amdgcn_rcpf(x); }
__device__ __forceinline__ float frsq(float x) { return __builtin_amdgcn_rsqf(x); }
__device__ __forceinline__ float sq(float x) { return x * x; }

// ln(1 + e^{-x}) for x >= 0, via HW v_exp_f32 (2^x) / v_log_f32 (log2 x)
__device__ __forceinline__ float sp_neg(float x) {
    return 0.69314718f * __builtin_amdgcn_logf(1.0f + __builtin_amdgcn_exp2f(-x * 1.44269504f));
}

// ---- full-math helpers (45-pair reg term keeps exact original math) ----
__device__ __forceinline__ float2 norm_pt(float x, float y) {
    if (x == 0.0f && y == 0.0f) { x = 1.0f; y = 1.0f; }
    float nrm = sqrtf(x * x + y * y);
    float inv = frcp(fmaxf(nrm, EPSF));
    return make_float2(x * inv, y * inv);
}

__device__ __forceinline__ float edge_cr_full(float x1, float y1, float x2, float y2) {
    float a = y1 - y2;
    float b = x2 - x1;
    float c = x1 * y2 - y1 * x2;
    float n2 = fmaxf(a * a + b * b, EPSF);
    float rn2 = frcp(n2);
    float x0 = -c * a * rn2;
    float y0 = -c * b * rn2;
    float t  = sqrtf(fmaxf(1.0f - c * c * rn2, 0.0f));
    float inv = frsq(n2);
    float px = -b * inv, py = a * inv;
    float2 q1 = norm_pt(x0 + t * px, y0 + t * py);
    float2 q2 = norm_pt(x0 - t * px, y0 - t * py);
    float d12 = sqrtf(sq(x1 - x2)   + sq(y1 - y2));
    float d34 = sqrtf(sq(q1.x - q2.x) + sq(q1.y - q2.y));
    float d13 = sqrtf(sq(x1 - q1.x) + sq(y1 - q1.y));
    float d24 = sqrtf(sq(x2 - q2.x) + sq(y2 - q2.y));
    float cr = d12 * d34 * frcp(d13 * d24 + EPSF);
    return fminf(fmaxf(cr, -5.0f), 5.0f);
}

__device__ __forceinline__ void block_reduce2(float v0, float v1, double* a0, double* a1) {
    #pragma unroll
    for (int o = 32; o > 0; o >>= 1) {
        v0 += __shfl_down(v0, o, 64);
        v1 += __shfl_down(v1, o, 64);
    }
    __shared__ float s0[8], s1[8];
    int lane = threadIdx.x & 63, wid = threadIdx.x >> 6;
    if (lane == 0) { s0[wid] = v0; s1[wid] = v1; }
    __syncthreads();
    if (threadIdx.x == 0) {
        float t0 = 0.0f, t1 = 0.0f;
        int nw = blockDim.x >> 6;
        for (int w = 0; w < nw; ++w) { t0 += s0[w]; t1 += s1[w]; }
        atomicAdd(a0, (double)t0);
        if (a1) atomicAdd(a1, (double)t1);
    }
}

// normalize z into a compact half2 table (4 MB for N=1M -> fits one XCD L2)
__global__ void norm_kernel(const float* __restrict__ z, __half2* __restrict__ tab, int N) {
    int stride = gridDim.x * blockDim.x;
    for (int i = blockIdx.x * blockDim.x + threadIdx.x; i < N; i += stride) {
        float2 p = ((const float2*)z)[i];
        float x = p.x, y = p.y;
        if (x == 0.0f && y == 0.0f) { x = 1.0f; y = 1.0f; }
        float inv = frcp(fmaxf(sqrtf(x * x + y * y), EPSF));
        tab[i] = __floats2half2_rn(x * inv, y * inv);
    }
}

// Fused pos+neg edge kernel, straight-line 16 edges/thread for max MLP.
// cr identity: i1==p1, i2==p2 on unit circle => cr = min(d12^2 * 1e8, 5).
template <bool USE_TAB>
__global__ __launch_bounds__(256)
void edge_kernel(const __half2* __restrict__ tab, const float* __restrict__ z,
                 const int* __restrict__ ei, int E,
                 const int* __restrict__ nei, int En,
                 const int* __restrict__ bsp, int N, int gp,
                 double* __restrict__ acc) {
    const bool is_pos = (int)blockIdx.x < gp;
    const int* idx;
    int cnt, blk0;
    if (is_pos) { idx = ei;  cnt = E;  blk0 = blockIdx.x; }
    else        { idx = nei; cnt = En; blk0 = blockIdx.x - gp; }
    const int* src = idx;
    const int* dst = idx + cnt;
    const int bs = bsp[0];
    const unsigned nm1 = (unsigned)(N - 1);

    float lsum = 0.0f, lcnt = 0.0f;
    long long base = ((long long)blk0 * blockDim.x + threadIdx.x) * EPT;

    if (base + EPT <= (long long)cnt) {
        // 1) index loads (8 x dwordx4, nontemporal)
        iv4 s4[EPT / 4], d4[EPT / 4];
        #pragma unroll
        for (int k = 0; k < EPT / 4; ++k) {
            s4[k] = __builtin_nontemporal_load((const iv4*)(src + base) + k);
            d4[k] = __builtin_nontemporal_load((const iv4*)(dst + base) + k);
        }
        // 2) 32 gathers into registers, all static indices
        __half2 ha[EPT], hb[EPT];
        float2 fa[EPT], fb[EPT];
        #pragma unroll
        for (int k = 0; k < EPT; ++k) {
            unsigned si = min((unsigned)s4[k >> 2][k & 3], nm1);
            unsigned di = min((unsigned)d4[k >> 2][k & 3], nm1);
            if (USE_TAB) {
                ha[k] = tab[si];
                hb[k] = tab[di];
            } else {
                fa[k] = ((const float2*)z)[si];
                fb[k] = ((const float2*)z)[di];
            }
        }
        // 3) compute
        #pragma unroll
        for (int k = 0; k < EPT; ++k) {
            float x1, y1, x2, y2;
            if (USE_TAB) {
                float2 a = __half22float2(ha[k]);
                float2 b = __half22float2(hb[k]);
                x1 = a.x; y1 = a.y; x2 = b.x; y2 = b.y;
            } else {
                float2 pa = norm_pt(fa[k].x, fa[k].y);
                float2 pb = norm_pt(fb[k].x, fb[k].y);
                x1 = pa.x; y1 = pa.y; x2 = pb.x; y2 = pb.y;
            }
            float dx = x1 - x2, dy = y1 - y2;
            float cr = fminf((dx * dx + dy * dy) * 1e8f, 5.0f);
            float t = sp_neg(cr);            // softplus(-cr), cr >= 0
            if (is_pos) {
                int s = s4[k >> 2][k & 3], d = d4[k >> 2][k & 3];
                float m = (s < bs && d < bs) ? 1.0f : 0.0f;
                lsum += t * m;
                lcnt += m;
            } else {
                lsum += cr + t;              // softplus(cr) = cr + softplus(-cr)
            }
        }
    } else {
        // tail: at most one thread straddles the end
        for (long long i = base; i < (long long)cnt; ++i) {
            int s = src[i], d = dst[i];
            unsigned si = min((unsigned)s, nm1);
            unsigned di = min((unsigned)d, nm1);
            float x1, y1, x2, y2;
            if (USE_TAB) {
                float2 a = __half22float2(tab[si]);
                float2 b = __half22float2(tab[di]);
                x1 = a.x; y1 = a.y; x2 = b.x; y2 = b.y;
            } else {
                float2 a = ((const float2*)z)[si];
                float2 b = ((const float2*)z)[di];
                float2 pa = norm_pt(a.x, a.y);
                float2 pb = norm_pt(b.x, b.y);
                x1 = pa.x; y1 = pa.y; x2 = pb.x; y2 = pb.y;
            }
            float dx = x1 - x2, dy = y1 - y2;
            float cr = fminf((dx * dx + dy * dy) * 1e8f, 5.0f);
            float t = sp_neg(cr);
            if (is_pos) {
                float m = (s < bs && d < bs) ? 1.0f : 0.0f;
                lsum += t * m; lcnt += m;
            } else {
                lsum += cr + t;
            }
        }
    }

    if (is_pos) block_reduce2(lsum, lcnt, &acc[0], &acc[1]);
    else        block_reduce2(lsum, 0.0f, &acc[2], nullptr);
}

// 45-pair regularizer + finalize fused (single block, runs after edge_kernel on stream)
__global__ void reg_fin_kernel(const float* __restrict__ z, const int* __restrict__ ridx,
                               int nreg, int N, const double* __restrict__ acc,
                               float* __restrict__ out, int nneg) {
    int t = threadIdx.x;
    int npairs = nreg * (nreg - 1) / 2;
    float v = 0.0f;
    for (int p = t; p < npairs; p += 64) {
        int idx = p, i = 0, cnt = nreg - 1;
        while (idx >= cnt) { idx -= cnt; ++i; --cnt; }
        int j = i + 1 + idx;
        unsigned si = min((unsigned)ridx[i], (unsigned)(N - 1));
        unsigned di = min((unsigned)ridx[j], (unsigned)(N - 1));
        float2 zs = *(const float2*)(z + 2u * si);
        float2 zd = *(const float2*)(z + 2u * di);
        float2 p1 = norm_pt(zs.x, zs.y);
        float2 p2 = norm_pt(zd.x, zd.y);
        float cr = edge_cr_full(p1.x, p1.y, p2.x, p2.y);
        v += fabsf(cr * cr - 1.0f);   // cr1 == cr2 (identical num/den products)
    }
    #pragma unroll
    for (int o = 32; o > 0; o >>= 1) v += __shfl_down(v, o, 64);
    if (t == 0) {
        double pos = acc[0] / fmax(acc[1], 1.0);
        double neg = acc[2] / (double)nneg;
        double reg = (double)v / (double)npairs;
        double tot = pos + neg + 0.1 * reg;
        tot = fmin(fmax(tot, 0.0), 5.0);
        out[0] = (float)tot;
    }
}

extern "C" void kernel_launch(void* const* d_in, const int* in_sizes, int n_in,
                              void* d_out, int out_size, void* d_ws, size_t ws_size,
                              hipStream_t stream) {
    const float* z  = (const float*)d_in[0];
    const int* ei   = (const int*)d_in[1];
    const int* nei  = (const int*)d_in[2];
    const int* ridx = (const int*)d_in[3];
    const int* bsp  = (const int*)d_in[4];
    float* out = (float*)d_out;

    int N    = in_sizes[0] / 2;
    int E    = in_sizes[1] / 2;
    int Nn   = in_sizes[2] / 2;
    int nreg = in_sizes[3];

    double* acc = (double*)d_ws;
    __half2* tab = (__half2*)((char*)d_ws + 256);
    size_t need = 256 + (size_t)N * sizeof(__half2);
    bool use_tab = (ws_size >= need);

    (void)hipMemsetAsync(acc, 0, 4 * sizeof(double), stream);

    const int threads = 256;
    const long long per_blk = (long long)threads * EPT;   // 4096 edges per block
    int gp = (int)((E  + per_blk - 1) / per_blk);
    int gn = (int)((Nn + per_blk - 1) / per_blk);

    if (use_tab) {
        int gnorm = (N + threads * 4 - 1) / (threads * 4); if (gnorm > 1024) gnorm = 1024;
        norm_kernel<<<gnorm, threads, 0, stream>>>(z, tab, N);
        edge_kernel<true><<<gp + gn, threads, 0, stream>>>(tab, z, ei, E, nei, Nn, bsp, N, gp, acc);
    } else {
        edge_kernel<false><<<gp + gn, threads, 0, stream>>>(nullptr, z, ei, E, nei, Nn, bsp, N, gp, acc);
    }
    reg_fin_kernel<<<1, 64, 0, stream>>>(z, ridx, nreg, N, acc, out, Nn);
}

// Round 6
// 109.556 us; speedup vs baseline: 1.9303x; 1.1262x over previous
//
#include <hip/hip_runtime.h>

#define EPSF 1e-8f
#define EPT 16  // edges per thread

typedef int iv4 __attribute__((ext_vector_type(4)));

__device__ __forceinline__ float frcp(float x) { return __builtin_amdgcn_rcpf(x); }
__device__ __forceinline__ float frsq(float x) { return __builtin_amdgcn_rsqf(x); }
__device__ __forceinline__ float sq(float x) { return x * x; }

// ln(1 + e^{-x}) for x >= 0, via HW v_exp_f32 (2^x) / v_log_f32 (log2 x)
__device__ __forceinline__ float sp_neg(float x) {
    return 0.69314718f * __builtin_amdgcn_logf(1.0f + __builtin_amdgcn_exp2f(-x * 1.44269504f));
}

// ---- full-math helpers (45-pair reg term keeps exact original math) ----
__device__ __forceinline__ float2 norm_pt(float x, float y) {
    if (x == 0.0f && y == 0.0f) { x = 1.0f; y = 1.0f; }
    float nrm = sqrtf(x * x + y * y);
    float inv = frcp(fmaxf(nrm, EPSF));
    return make_float2(x * inv, y * inv);
}

__device__ __forceinline__ float edge_cr_full(float x1, float y1, float x2, float y2) {
    float a = y1 - y2;
    float b = x2 - x1;
    float c = x1 * y2 - y1 * x2;
    float n2 = fmaxf(a * a + b * b, EPSF);
    float rn2 = frcp(n2);
    float x0 = -c * a * rn2;
    float y0 = -c * b * rn2;
    float t  = sqrtf(fmaxf(1.0f - c * c * rn2, 0.0f));
    float inv = frsq(n2);
    float px = -b * inv, py = a * inv;
    float2 q1 = norm_pt(x0 + t * px, y0 + t * py);
    float2 q2 = norm_pt(x0 - t * px, y0 - t * py);
    float d12 = sqrtf(sq(x1 - x2)   + sq(y1 - y2));
    float d34 = sqrtf(sq(q1.x - q2.x) + sq(q1.y - q2.y));
    float d13 = sqrtf(sq(x1 - q1.x) + sq(y1 - q1.y));
    float d24 = sqrtf(sq(x2 - q2.x) + sq(y2 - q2.y));
    float cr = d12 * d34 * frcp(d13 * d24 + EPSF);
    return fminf(fmaxf(cr, -5.0f), 5.0f);
}

__device__ __forceinline__ void block_reduce2(float v0, float v1, double* a0, double* a1) {
    #pragma unroll
    for (int o = 32; o > 0; o >>= 1) {
        v0 += __shfl_down(v0, o, 64);
        v1 += __shfl_down(v1, o, 64);
    }
    __shared__ float s0[8], s1[8];
    int lane = threadIdx.x & 63, wid = threadIdx.x >> 6;
    if (lane == 0) { s0[wid] = v0; s1[wid] = v1; }
    __syncthreads();
    if (threadIdx.x == 0) {
        float t0 = 0.0f, t1 = 0.0f;
        int nw = blockDim.x >> 6;
        for (int w = 0; w < nw; ++w) { t0 += s0[w]; t1 += s1[w]; }
        atomicAdd(a0, (double)t0);
        if (a1) atomicAdd(a1, (double)t1);
    }
}

// Encode each point as a 16-bit angle (2 MB table, fits one XCD L2 with headroom).
// atan2 is scale-invariant -> no normalize needed. Quant err 2pi/65536 ~ 1e-4 rad,
// better than the previous half2 encoding.
__global__ void norm_kernel(const float* __restrict__ z, unsigned short* __restrict__ tab, int N) {
    int stride = gridDim.x * blockDim.x;
    for (int i = blockIdx.x * blockDim.x + threadIdx.x; i < N; i += stride) {
        float2 p = ((const float2*)z)[i];
        float x = p.x, y = p.y;
        if (x == 0.0f && y == 0.0f) { x = 1.0f; y = 1.0f; }
        float ang = atan2f(y, x);                     // [-pi, pi]
        int u = (int)lrintf(ang * 10430.378350470453f); // 65536/(2*pi)
        tab[i] = (unsigned short)(u & 0xFFFF);
    }
}

// Fused pos+neg edge kernel. cr identity chain:
//   i1==p1, i2==p2 on unit circle => cr = min(d12^2 * 1e8, 5)
//   d12^2 = 4 sin^2(dTheta/2), dTheta via exact mod-2^16 integer wrap.
// One __sinf per edge; sin is accurate near 0 (no 2-2cos cancellation).
template <bool USE_TAB>
__global__ __launch_bounds__(256)
void edge_kernel(const unsigned short* __restrict__ tab, const float* __restrict__ z,
                 const int* __restrict__ ei, int E,
                 const int* __restrict__ nei, int En,
                 const int* __restrict__ bsp, int N, int gp,
                 double* __restrict__ acc) {
    const bool is_pos = (int)blockIdx.x < gp;
    const int* idx;
    int cnt, blk0;
    if (is_pos) { idx = ei;  cnt = E;  blk0 = blockIdx.x; }
    else        { idx = nei; cnt = En; blk0 = blockIdx.x - gp; }
    const int* src = idx;
    const int* dst = idx + cnt;
    const int bs = bsp[0];
    const unsigned nm1 = (unsigned)(N - 1);

    float lsum = 0.0f, lcnt = 0.0f;
    long long base = ((long long)blk0 * blockDim.x + threadIdx.x) * EPT;

    if (base + EPT <= (long long)cnt) {
        iv4 s4[EPT / 4], d4[EPT / 4];
        #pragma unroll
        for (int k = 0; k < EPT / 4; ++k) {
            s4[k] = __builtin_nontemporal_load((const iv4*)(src + base) + k);
            d4[k] = __builtin_nontemporal_load((const iv4*)(dst + base) + k);
        }
        unsigned short ua[EPT], ub[EPT];
        float2 fa[EPT], fb[EPT];
        #pragma unroll
        for (int k = 0; k < EPT; ++k) {
            unsigned si = min((unsigned)s4[k >> 2][k & 3], nm1);
            unsigned di = min((unsigned)d4[k >> 2][k & 3], nm1);
            if (USE_TAB) {
                ua[k] = tab[si];
                ub[k] = tab[di];
            } else {
                fa[k] = ((const float2*)z)[si];
                fb[k] = ((const float2*)z)[di];
            }
        }
        #pragma unroll
        for (int k = 0; k < EPT; ++k) {
            float d2;
            if (USE_TAB) {
                int du = (short)(unsigned short)(ua[k] - ub[k]);  // exact mod-2^16 wrap
                float s = __sinf((float)du * 4.7936899621426287e-5f);  // pi/65536
                d2 = 4.0f * s * s;
            } else {
                float2 pa = norm_pt(fa[k].x, fa[k].y);
                float2 pb = norm_pt(fb[k].x, fb[k].y);
                float dx = pa.x - pb.x, dy = pa.y - pb.y;
                d2 = dx * dx + dy * dy;
            }
            float cr = fminf(d2 * 1e8f, 5.0f);
            float t = sp_neg(cr);            // softplus(-cr), cr >= 0
            if (is_pos) {
                int s = s4[k >> 2][k & 3], d = d4[k >> 2][k & 3];
                float m = (s < bs && d < bs) ? 1.0f : 0.0f;
                lsum += t * m;
                lcnt += m;
            } else {
                lsum += cr + t;              // softplus(cr) = cr + softplus(-cr)
            }
        }
    } else {
        for (long long i = base; i < (long long)cnt; ++i) {
            int s = src[i], d = dst[i];
            unsigned si = min((unsigned)s, nm1);
            unsigned di = min((unsigned)d, nm1);
            float d2;
            if (USE_TAB) {
                int du = (short)(unsigned short)(tab[si] - tab[di]);
                float ss = __sinf((float)du * 4.7936899621426287e-5f);
                d2 = 4.0f * ss * ss;
            } else {
                float2 a = ((const float2*)z)[si];
                float2 b = ((const float2*)z)[di];
                float2 pa = norm_pt(a.x, a.y);
                float2 pb = norm_pt(b.x, b.y);
                float dx = pa.x - pb.x, dy = pa.y - pb.y;
                d2 = dx * dx + dy * dy;
            }
            float cr = fminf(d2 * 1e8f, 5.0f);
            float t = sp_neg(cr);
            if (is_pos) {
                float m = (s < bs && d < bs) ? 1.0f : 0.0f;
                lsum += t * m; lcnt += m;
            } else {
                lsum += cr + t;
            }
        }
    }

    if (is_pos) block_reduce2(lsum, lcnt, &acc[0], &acc[1]);
    else        block_reduce2(lsum, 0.0f, &acc[2], nullptr);
}

// 45-pair regularizer + finalize fused
__global__ void reg_fin_kernel(const float* __restrict__ z, const int* __restrict__ ridx,
                               int nreg, int N, const double* __restrict__ acc,
                               float* __restrict__ out, int nneg) {
    int t = threadIdx.x;
    int npairs = nreg * (nreg - 1) / 2;
    float v = 0.0f;
    for (int p = t; p < npairs; p += 64) {
        int idx = p, i = 0, cnt = nreg - 1;
        while (idx >= cnt) { idx -= cnt; ++i; --cnt; }
        int j = i + 1 + idx;
        unsigned si = min((unsigned)ridx[i], (unsigned)(N - 1));
        unsigned di = min((unsigned)ridx[j], (unsigned)(N - 1));
        float2 zs = *(const float2*)(z + 2u * si);
        float2 zd = *(const float2*)(z + 2u * di);
        float2 p1 = norm_pt(zs.x, zs.y);
        float2 p2 = norm_pt(zd.x, zd.y);
        float cr = edge_cr_full(p1.x, p1.y, p2.x, p2.y);
        v += fabsf(cr * cr - 1.0f);   // cr1 == cr2 (identical num/den products)
    }
    #pragma unroll
    for (int o = 32; o > 0; o >>= 1) v += __shfl_down(v, o, 64);
    if (t == 0) {
        double pos = acc[0] / fmax(acc[1], 1.0);
        double neg = acc[2] / (double)nneg;
        double reg = (double)v / (double)npairs;
        double tot = pos + neg + 0.1 * reg;
        tot = fmin(fmax(tot, 0.0), 5.0);
        out[0] = (float)tot;
    }
}

extern "C" void kernel_launch(void* const* d_in, const int* in_sizes, int n_in,
                              void* d_out, int out_size, void* d_ws, size_t ws_size,
                              hipStream_t stream) {
    const float* z  = (const float*)d_in[0];
    const int* ei   = (const int*)d_in[1];
    const int* nei  = (const int*)d_in[2];
    const int* ridx = (const int*)d_in[3];
    const int* bsp  = (const int*)d_in[4];
    float* out = (float*)d_out;

    int N    = in_sizes[0] / 2;
    int E    = in_sizes[1] / 2;
    int Nn   = in_sizes[2] / 2;
    int nreg = in_sizes[3];

    double* acc = (double*)d_ws;
    unsigned short* tab = (unsigned short*)((char*)d_ws + 256);
    size_t need = 256 + (size_t)N * sizeof(unsigned short);
    bool use_tab = (ws_size >= need);

    (void)hipMemsetAsync(acc, 0, 4 * sizeof(double), stream);

    const int threads = 256;
    const long long per_blk = (long long)threads * EPT;   // 4096 edges per block
    int gp = (int)((E  + per_blk - 1) / per_blk);
    int gn = (int)((Nn + per_blk - 1) / per_blk);

    if (use_tab) {
        int gnorm = (N + threads * 4 - 1) / (threads * 4); if (gnorm > 1024) gnorm = 1024;
        norm_kernel<<<gnorm, threads, 0, stream>>>(z, tab, N);
        edge_kernel<true><<<gp + gn, threads, 0, stream>>>(tab, z, ei, E, nei, Nn, bsp, N, gp, acc);
    } else {
        edge_kernel<false><<<gp + gn, threads, 0, stream>>>(nullptr, z, ei, E, nei, Nn, bsp, N, gp, acc);
    }
    reg_fin_kernel<<<1, 64, 0, stream>>>(z, ridx, nreg, N, acc, out, Nn);
}